// Round 10
// baseline (53.791 us; speedup 1.0000x reference)
//
#include <hip/hip_runtime.h>
#include <hip/hip_bf16.h>

#define B_ 8
#define N_ 16384
#define S_ 1024
#define K_ 32
#define CSTEM 64
#define CPATCH 128
#define INDIM 91
#define LDA 104     // As row stride (bf16)
#define LDH 136     // Hs row stride (bf16)
#define NQ 2        // patches per MLP block (LDS 22KB -> 7 blocks/CU)

typedef __attribute__((ext_vector_type(8))) short short8v;  // 8 bf16 = 4 VGPRs
typedef __attribute__((ext_vector_type(4))) float f32x4;

static __device__ __forceinline__ unsigned short f2bf(float f) {
  union { float f; unsigned int u; } v; v.f = f;
  return (unsigned short)((v.u + 0x7FFFu + ((v.u >> 16) & 1u)) >> 16);  // RNE
}

// -------- Kernel 0: pack w1/w2 into MFMA B-fragment order (bf16) --------
__global__ __launch_bounds__(256) void pack_weights(
    const float* __restrict__ w1, const float* __restrict__ w2,
    unsigned short* __restrict__ w1p, unsigned short* __restrict__ w2p)
{
  const int id = blockIdx.x * 256 + threadIdx.x;
  if (id < 3 * 8 * 64) {                       // w1: K padded 91->96 (3 ksteps)
    const int l = id & 63, ct = (id >> 6) & 7, ks = id >> 9;
    const int col = 16 * ct + (l & 15);
    const int kb = 32 * ks + (l >> 4) * 8;
    unsigned short v[8];
    #pragma unroll
    for (int j = 0; j < 8; ++j) {
      const int k = kb + j;
      v[j] = (k < INDIM) ? f2bf(w1[k * CPATCH + col]) : (unsigned short)0;
    }
    *(short8v*)&w1p[(size_t)id * 8] = *(const short8v*)v;
  } else if (id < 3 * 8 * 64 + 4 * 8 * 64) {   // w2: 4 ksteps
    const int id2 = id - 3 * 8 * 64;
    const int l = id2 & 63, ct = (id2 >> 6) & 7, ks = id2 >> 9;
    const int col = 16 * ct + (l & 15);
    const int kb = 32 * ks + (l >> 4) * 8;
    unsigned short v[8];
    #pragma unroll
    for (int j = 0; j < 8; ++j) v[j] = f2bf(w2[(kb + j) * CPATCH + col]);
    *(short8v*)&w2p[(size_t)id2 * 8] = *(const short8v*)v;
  }
}

// component accessor for an unrolled float4 array (IDX must be compile-time)
#define FCOMP(V, IDX) (((IDX) & 3) == 0 ? (V)[(IDX) >> 2].x : \
                       ((IDX) & 3) == 1 ? (V)[(IDX) >> 2].y : \
                       ((IDX) & 3) == 2 ? (V)[(IDX) >> 2].z : (V)[(IDX) >> 2].w)

// -------- Kernel 1: ball query, wave-per-query, barrier-free (R9 math) ----
// 2048 blocks x 4 independent waves = 8192 waves == chip wave capacity:
// every query resident at once; total time ~= slowest single query.
// Distance decisions bit-identical to the verified f32-band+f64 expression.
__global__ __launch_bounds__(256) void ball_query_kernel(
    const float* __restrict__ xyz, const float* __restrict__ pc,
    float* __restrict__ idx_out)
{
  const int lane = threadIdx.x & 63;
  const int w    = threadIdx.x >> 6;
  const int bs   = blockIdx.x * 4 + w;
  const int b    = bs >> 10;                   // S_ = 1024

  __shared__ int sidx[4][K_];

  const float* __restrict__ xb = xyz + (size_t)b * N_ * 3;
  const float cx = pc[bs * 3 + 0];
  const float cy = pc[bs * 3 + 1];
  const float cz = pc[bs * 3 + 2];
  const double rr = 0.2 * 0.2;

  int found = 0;
  for (int base = 0; base < N_; base += 1024) {
    const int i0 = base + lane * 16;           // 16 consecutive pts per lane
    float4 v[12];
    #pragma unroll
    for (int t = 0; t < 12; ++t)
      v[t] = *(const float4*)&xb[i0 * 3 + t * 4];

    unsigned mask = 0u;
    #pragma unroll
    for (int p = 0; p < 16; ++p) {
      const float X = FCOMP(v, 3 * p + 0);
      const float Y = FCOMP(v, 3 * p + 1);
      const float Z = FCOMP(v, 3 * p + 2);
      const float dxf = X - cx, dyf = Y - cy, dzf = Z - cz;
      const float d2f = fmaf(dxf, dxf, fmaf(dyf, dyf, dzf * dzf));
      bool in;
      if (fabsf(d2f - 0.04f) <= 1e-5f) {       // rare exact f64 recheck
        const double dx = (double)X - (double)cx;
        const double dy = (double)Y - (double)cy;
        const double dz = (double)Z - (double)cz;
        in = (dx * dx + dy * dy + dz * dz) <= rr;
      } else {
        in = (d2f < 0.04f);
      }
      if (in) mask |= (1u << p);
    }

    const int cnt = __popc(mask);
    int incl = cnt;                            // wave-inclusive prefix
    #pragma unroll
    for (int d = 1; d < 64; d <<= 1) {
      const int t = __shfl_up(incl, d);
      if (lane >= d) incl += t;
    }
    const int tot = __shfl(incl, 63);

    int pos = found + (incl - cnt);
    #pragma unroll
    for (int p = 0; p < 16; ++p) {             // static p: no dyn reg indexing
      if (mask & (1u << p)) {
        if (pos < K_) sidx[w][pos] = i0 + p;
        ++pos;
      }
    }
    found += tot;
    if (found >= K_) break;                    // wave-uniform
  }

  if (lane == 0 && found == 0) sidx[w][0] = N_ - 1;
  __threadfence_block();                       // wave-local LDS drain (R3-verified)
  if (lane < K_) {
    const int fill = sidx[w][0];
    const int v = (lane < found) ? sidx[w][lane] : fill;
    idx_out[(size_t)bs * K_ + lane] = (float)v;
  }
}

// -------- Kernel 2: gather + PE + bf16-MFMA MLP + max (R7 body, NQ=2) -----
__global__ __launch_bounds__(256) void patch_mlp_mfma(
    const float* __restrict__ xyz, const float* __restrict__ pf,
    const float* __restrict__ pc,
    const unsigned short* __restrict__ w1p, const float* __restrict__ b1,
    const unsigned short* __restrict__ w2p, const float* __restrict__ b2,
    const float* __restrict__ idx_f, float* __restrict__ out)
{
  const int tid  = threadIdx.x;
  const int lane = tid & 63;
  const int w    = tid >> 6;
  const int bs0  = blockIdx.x * NQ;
  const int b    = bs0 >> 10;                  // S_ = 1024, NQ | S_

  __shared__ float scen[3 * NQ];
  __shared__ int   sidx[NQ][K_];
  __shared__ __align__(16) unsigned short As[NQ * K_][LDA];
  __shared__ __align__(16) unsigned short Hs[K_][LDH];

  const float* __restrict__ xb  = xyz + (size_t)b * N_ * 3;
  const float* __restrict__ pfb = pf  + (size_t)b * N_ * CSTEM;

  if (tid < 3 * NQ) scen[tid] = pc[bs0 * 3 + tid];
  if (tid < NQ * K_) {
    const int q = tid >> 5, j = tid & 31;
    sidx[q][j] = (int)idx_f[(size_t)(bs0 + q) * K_ + j];
  }
  __syncthreads();

  // ---- Weight fragments + biases (register-resident, amortized over NQ) ----
  short8v w1f[3][2], w2f[4][2];
  #pragma unroll
  for (int ks = 0; ks < 3; ++ks)
    #pragma unroll
    for (int t = 0; t < 2; ++t)
      w1f[ks][t] = *(const short8v*)&w1p[((size_t)(ks * 8 + 2 * w + t) * 64 + lane) * 8];
  #pragma unroll
  for (int ks = 0; ks < 4; ++ks)
    #pragma unroll
    for (int t = 0; t < 2; ++t)
      w2f[ks][t] = *(const short8v*)&w2p[((size_t)(ks * 8 + 2 * w + t) * 64 + lane) * 8];
  const float bias1[2] = { b1[32 * w + (lane & 15)], b1[32 * w + 16 + (lane & 15)] };
  const float bias2[2] = { b2[32 * w + (lane & 15)], b2[32 * w + 16 + (lane & 15)] };

  // ---- Batched gather: both patches staged before any MFMA ----
  {
    const int row = tid >> 3, sub = tid & 7;   // feature loads, 8 thr/row
    #pragma unroll
    for (int q = 0; q < NQ; ++q) {
      const int r = sidx[q][row];
      const float4 f0 = *(const float4*)&pfb[(size_t)r * CSTEM + sub * 8];
      const float4 f1 = *(const float4*)&pfb[(size_t)r * CSTEM + sub * 8 + 4];
      unsigned short vv[8];
      vv[0] = f2bf(f0.x); vv[1] = f2bf(f0.y); vv[2] = f2bf(f0.z); vv[3] = f2bf(f0.w);
      vv[4] = f2bf(f1.x); vv[5] = f2bf(f1.y); vv[6] = f2bf(f1.z); vv[7] = f2bf(f1.w);
      *(short8v*)&As[q * K_ + row][sub * 8] = *(const short8v*)vv;
    }
  }
  {
    const int row = tid & 31, j = tid >> 5;    // rel+PE, 8 thr/row x 4 cols
    #pragma unroll
    for (int q = 0; q < NQ; ++q) {
      const int r = sidx[q][row];
      const float r0 = xb[r * 3 + 0] - scen[q * 3 + 0];
      const float r1 = xb[r * 3 + 1] - scen[q * 3 + 1];
      const float r2 = xb[r * 3 + 2] - scen[q * 3 + 2];
      #pragma unroll
      for (int cc = 0; cc < 4; ++cc) {
        const int c = 64 + 4 * j + cc;
        float val;
        if (c < 67) val = (c == 64) ? r0 : ((c == 65) ? r1 : r2);
        else if (c < 91) {
          const int qq = c - 67, d = qq >> 3, rbit = qq & 7, band = rbit & 3;
          const float rel = (d == 0) ? r0 : ((d == 1) ? r1 : r2);
          const float ang = rel * ((float)(1 << band) * 3.14159265358979323846f);
          val = (rbit < 4) ? __sinf(ang) : __cosf(ang);
        } else val = 0.f;
        As[q * K_ + row][c] = f2bf(val);
      }
    }
  }
  __syncthreads();

  // ---- Per patch: L1 MFMA -> relu -> Hs -> L2 MFMA -> column max ----
  #pragma unroll 1
  for (int q = 0; q < NQ; ++q) {
    f32x4 acc[2][2] = {};
    #pragma unroll
    for (int ks = 0; ks < 3; ++ks) {
      const int k0 = ks * 32 + (lane >> 4) * 8;
      const short8v a0 = *(const short8v*)&As[q * K_ + (lane & 15)][k0];
      const short8v a1 = *(const short8v*)&As[q * K_ + 16 + (lane & 15)][k0];
      acc[0][0] = __builtin_amdgcn_mfma_f32_16x16x32_bf16(a0, w1f[ks][0], acc[0][0], 0, 0, 0);
      acc[0][1] = __builtin_amdgcn_mfma_f32_16x16x32_bf16(a0, w1f[ks][1], acc[0][1], 0, 0, 0);
      acc[1][0] = __builtin_amdgcn_mfma_f32_16x16x32_bf16(a1, w1f[ks][0], acc[1][0], 0, 0, 0);
      acc[1][1] = __builtin_amdgcn_mfma_f32_16x16x32_bf16(a1, w1f[ks][1], acc[1][1], 0, 0, 0);
    }
    #pragma unroll
    for (int rt = 0; rt < 2; ++rt)
      #pragma unroll
      for (int t = 0; t < 2; ++t)
        #pragma unroll
        for (int reg = 0; reg < 4; ++reg) {
          const float h = fmaxf(acc[rt][t][reg] + bias1[t], 0.f);
          const int row = 16 * rt + (lane >> 4) * 4 + reg;
          const int col = 32 * w + 16 * t + (lane & 15);
          Hs[row][col] = f2bf(h);
        }
    __syncthreads();

    f32x4 acc2[2][2] = {};
    #pragma unroll
    for (int ks = 0; ks < 4; ++ks) {
      const int k0 = ks * 32 + (lane >> 4) * 8;
      const short8v a0 = *(const short8v*)&Hs[(lane & 15)][k0];
      const short8v a1 = *(const short8v*)&Hs[16 + (lane & 15)][k0];
      acc2[0][0] = __builtin_amdgcn_mfma_f32_16x16x32_bf16(a0, w2f[ks][0], acc2[0][0], 0, 0, 0);
      acc2[0][1] = __builtin_amdgcn_mfma_f32_16x16x32_bf16(a0, w2f[ks][1], acc2[0][1], 0, 0, 0);
      acc2[1][0] = __builtin_amdgcn_mfma_f32_16x16x32_bf16(a1, w2f[ks][0], acc2[1][0], 0, 0, 0);
      acc2[1][1] = __builtin_amdgcn_mfma_f32_16x16x32_bf16(a1, w2f[ks][1], acc2[1][1], 0, 0, 0);
    }
    float m0 = -3.4e38f, m1 = -3.4e38f;
    #pragma unroll
    for (int rt = 0; rt < 2; ++rt)
      #pragma unroll
      for (int reg = 0; reg < 4; ++reg) {
        m0 = fmaxf(m0, acc2[rt][0][reg]);
        m1 = fmaxf(m1, acc2[rt][1][reg]);
      }
    m0 += bias2[0];
    m1 += bias2[1];
    m0 = fmaxf(m0, __shfl_xor(m0, 16));
    m0 = fmaxf(m0, __shfl_xor(m0, 32));
    m1 = fmaxf(m1, __shfl_xor(m1, 16));
    m1 = fmaxf(m1, __shfl_xor(m1, 32));
    if (lane < 16) {
      out[(size_t)(bs0 + q) * CPATCH + 32 * w + lane]      = m0;
      out[(size_t)(bs0 + q) * CPATCH + 32 * w + 16 + lane] = m1;
    }
    __syncthreads();                           // Hs reuse next patch
  }
}

extern "C" void kernel_launch(void* const* d_in, const int* in_sizes, int n_in,
                              void* d_out, int out_size, void* d_ws, size_t ws_size,
                              hipStream_t stream) {
  const float* xyz = (const float*)d_in[0];
  const float* pf  = (const float*)d_in[1];
  const float* pc  = (const float*)d_in[2];
  const float* w1  = (const float*)d_in[3];
  const float* b1  = (const float*)d_in[4];
  const float* w2  = (const float*)d_in[5];
  const float* b2  = (const float*)d_in[6];

  float* out     = (float*)d_out;
  float* idx_out = out + (size_t)B_ * S_ * CPATCH;

  unsigned short* w1p = (unsigned short*)d_ws;
  unsigned short* w2p = w1p + 96 * 128;

  pack_weights<<<14, 256, 0, stream>>>(w1, w2, w1p, w2p);
  ball_query_kernel<<<B_ * S_ / 4, 256, 0, stream>>>(xyz, pc, idx_out);
  patch_mlp_mfma<<<B_ * S_ / NQ, 256, 0, stream>>>(xyz, pf, pc, w1p, b1, w2p, b2,
                                                   idx_out, out);
}